// Round 5
// baseline (374.051 us; speedup 1.0000x reference)
//
#include <hip/hip_runtime.h>

#define NB 16
#define NTQ 256
#define NTK 256
#define ND 256
#define NF 36
#define NH 8
#define NDK 32
#define NSF 6

typedef __attribute__((ext_vector_type(8))) short short8;
typedef __attribute__((ext_vector_type(4))) float f32x4;
#define MFMA16(a,b,c) __builtin_amdgcn_mfma_f32_16x16x32_bf16(a,b,c,0,0,0)

// ---- workspace byte offsets ----
// WqT/WkT hi/lo: [j*32+dk][d] bf16, 128KB each
#define WQTH_OFF 0u
#define WQTL_OFF (WQTH_OFF + 131072u)
#define WKTH_OFF (WQTH_OFF + 262144u)
#define WKTL_OFF (WQTH_OFF + 393216u)
// RT: [b][80][256] bf16 (f'=2f: m*v, f'=2f+1: m)
#define RT_OFF   (WQTH_OFF + 524288u)
// projected Q/K hi/lo: [b][j][t][dk] bf16, 4MB each
#define QPH_OFF  (2u*1024*1024)
#define QPL_OFF  (6u*1024*1024)
#define KPH_OFF  (10u*1024*1024)
#define KPL_OFF  (14u*1024*1024)
// HD: fp32 [b][j][t][f]
#define HD_OFF   (18u*1024*1024)
// grid-barrier counters (zeroed by captured hipMemsetAsync each replay)
#define CNT_OFF  (24u*1024*1024)

#define NBLK 512u

__device__ __forceinline__ short f2bf(float x){
    union { float f; unsigned u; } v; v.f = x;
    unsigned r = v.u + 0x7fffu + ((v.u >> 16) & 1u);
    return (short)(r >> 16);
}
__device__ __forceinline__ float bf2f(short s){
    union { float f; unsigned u; } v; v.u = ((unsigned)(unsigned short)s) << 16;
    return v.f;
}
__device__ __forceinline__ float fast_tanh(float x){
    float e = __expf(2.0f*x);
    return 1.0f - 2.0f/(e + 1.0f);
}
__device__ __forceinline__ short8 ld8(const short* p){ return *(const short8*)p; }

// hi/lo bf16 split of 8 consecutive floats (RNE hi, RNE residual lo)
__device__ __forceinline__ void cvt8(const float* __restrict__ p, short8& h8, short8& l8){
    f32x4 a = *(const f32x4*)p;
    f32x4 c = *(const f32x4*)(p + 4);
    #pragma unroll
    for (int i = 0; i < 4; ++i){
        short h0 = f2bf(a[i]); h8[i]   = h0; l8[i]   = f2bf(a[i] - bf2f(h0));
        short h1 = f2bf(c[i]); h8[4+i] = h1; l8[4+i] = f2bf(c[i] - bf2f(h1));
    }
}

// device-scope software grid barrier; all NBLK blocks are co-resident
// (grid 512 <= capacity 1024 from __launch_bounds__(256,4)).
// Bounded spin: if co-residency ever fails we produce wrong results, not a hang.
__device__ __forceinline__ void gridbar(unsigned* cnt){
    __syncthreads();
    if (threadIdx.x == 0){
        __threadfence();   // release: publish this block's global writes (agent scope)
        __hip_atomic_fetch_add(cnt, 1u, __ATOMIC_ACQ_REL, __HIP_MEMORY_SCOPE_AGENT);
        unsigned it = 0;
        while (__hip_atomic_load(cnt, __ATOMIC_ACQUIRE, __HIP_MEMORY_SCOPE_AGENT) < NBLK
               && ++it < (1u << 17))
            __builtin_amdgcn_s_sleep(2);
        __threadfence();   // acquire: invalidate stale lines on this CU
    }
    __syncthreads();
}

// ================= single kernel: pack -> proj -> attn -> final =================
// grid 512 x 256thr; LDS 8.45KB; VGPR capped at 128 -> >=4 blocks/CU capacity.
__global__ __launch_bounds__(256, 4)
void imta_all(const float* __restrict__ query, const float* __restrict__ key_ts,
              const float* __restrict__ value, const float* __restrict__ mask,
              const float* __restrict__ Wq, const float* __restrict__ Wk,
              const float* __restrict__ Wc, const float* __restrict__ bc,
              const float* __restrict__ Wo1, const float* __restrict__ bo1,
              const float* __restrict__ Wo2, const float* __restrict__ bo2,
              char* __restrict__ wsb, float* __restrict__ out){
    const int bid = blockIdx.x, tid = threadIdx.x;
    const int w = tid >> 6, lane = tid & 63;
    const int col = lane & 15, quad = lane >> 4;
    unsigned* cnts = (unsigned*)(wsb + CNT_OFF);
    __shared__ __align__(16) short sBuf[16*264];   // 8.45 KB, reused across phases

    // ---------------- phase A: pack (W transpose + RT) ----------------
    {
        // W: all 512 blocks, 1 elem/thread (131072 = 2 arrays * 65536)
        const int idx = bid*256 + tid;
        const int arr = idx >> 16, rem = idx & 65535;
        const int d = rem & 255, jdk = rem >> 8;
        const int jj = jdk >> 5, dk = jdk & 31;
        const float* __restrict__ W = arr ? Wk : Wq;
        float v = W[(jj*ND + d)*NDK + dk];
        short h = f2bf(v);
        short* oh = (short*)(wsb + (arr ? WKTH_OFF : WQTH_OFF));
        short* ol = (short*)(wsb + (arr ? WKTL_OFF : WQTL_OFF));
        oh[rem] = h; ol[rem] = f2bf(v - bf2f(h));
    }
    if (bid < 256){
        const int x = bid & 15, b = bid >> 4;
        const int k = tid;
        short* rt = (short*)(wsb + RT_OFF) + b*80*256;
        #pragma unroll
        for (int r = 0; r < 5; ++r){
            const int fp = x*5 + r;
            const int f = fp >> 1;
            short o = 0;
            if (f < NF){
                float m = mask[(b*NTK + k)*NF + f];
                o = (fp & 1) ? f2bf(m) : f2bf(m * value[(b*NTK + k)*NF + f]);
            }
            rt[fp*256 + k] = o;
        }
    }
    gridbar(cnts + 0);

    // ---------------- phase B: projection GEMM (R3-verified body, 4 units/block) ----------------
    for (int i = 0; i < 4; ++i){
        const unsigned u = (unsigned)bid + NBLK*i;      // 2048 units
        const int x = u & 63, side = (u >> 6) & 1, b = u >> 7;
        const int t0 = (x >> 2)*16, c0 = (x & 3)*64;
        const float* __restrict__ X = side ? key_ts : query;
        const short* WH = (const short*)(wsb + (side ? WKTH_OFF : WQTH_OFF));
        const short* WL = (const short*)(wsb + (side ? WKTL_OFF : WQTL_OFF));
        short* OH = (short*)(wsb + (side ? KPH_OFF : QPH_OFF));
        short* OL = (short*)(wsb + (side ? KPL_OFF : QPL_OFF));

        const int n = c0 + w*16 + col;
        const float* xrow = X + (size_t)(b*NTQ + t0 + col)*ND;

        f32x4 acc = (f32x4)0.f;
        #pragma unroll
        for (int kb = 0; kb < 8; ++kb){
            const int dko = kb*32 + quad*8;
            short8 ah, al;
            cvt8(xrow + dko, ah, al);
            short8 bh = ld8(WH + n*ND + dko);
            short8 bl = ld8(WL + n*ND + dko);
            acc = MFMA16(al, bh, acc);
            acc = MFMA16(ah, bl, acc);
            acc = MFMA16(ah, bh, acc);
        }
        const int j = n >> 5, dk = n & 31;
        #pragma unroll
        for (int r = 0; r < 4; ++r){
            const int t = t0 + quad*4 + r;
            float v = acc[r];
            short h = f2bf(v);
            size_t o = (size_t)(((b*NH + j)*NTQ + t)*NDK + dk);
            OH[o] = h; OL[o] = f2bf(v - bf2f(h));
        }
    }
    gridbar(cnts + 1);

    // ---------------- phase C: attention (R3-verified 16-q body, 4 units/block) ----------------
    for (int i = 0; i < 4; ++i){
        const unsigned u = (unsigned)bid + NBLK*i;      // 2048 units
        const int xq = u & 15, j = (u >> 4) & 7, b = u >> 7;
        const int t0 = xq*16;
        short* const sE = sBuf;                         // [16][264]
        const short* QH = (const short*)(wsb + QPH_OFF) + (b*NH + j)*NTQ*NDK;
        const short* QL = (const short*)(wsb + QPL_OFF) + (b*NH + j)*NTQ*NDK;
        const short* KH = (const short*)(wsb + KPH_OFF) + (b*NH + j)*NTK*NDK;
        const short* KL = (const short*)(wsb + KPL_OFF) + (b*NH + j)*NTK*NDK;
        const short* RT = (const short*)(wsb + RT_OFF) + b*80*256;
        float* HD = (float*)(wsb + HD_OFF) + (b*NH + j)*NTQ*NF;

        __syncthreads();                                // protect sBuf from prior unit
        short8 ah = ld8(QH + (t0 + col)*NDK + quad*8);
        short8 al = ld8(QL + (t0 + col)*NDK + quad*8);
        #pragma unroll
        for (int nt = 0; nt < 4; ++nt){
            const int key0 = w*64 + nt*16;
            short8 bh = ld8(KH + (key0 + col)*NDK + quad*8);
            short8 bl = ld8(KL + (key0 + col)*NDK + quad*8);
            f32x4 c = (f32x4)0.f;
            c = MFMA16(al, bh, c);
            c = MFMA16(ah, bl, c);
            c = MFMA16(ah, bh, c);
            const int key = key0 + col;
            #pragma unroll
            for (int r = 0; r < 4; ++r)
                sE[(quad*4 + r)*264 + key] = f2bf(__expf(c[r]));
        }
        __syncthreads();

        f32x4 accA = (f32x4)0.f, accB = (f32x4)0.f;
        #pragma unroll 2
        for (int kb = 0; kb < 8; ++kb){
            const int ko = kb*32 + quad*8;
            short8 a = *(const short8*)&sE[col*264 + ko];
            short8 bb = ld8(RT + (w*16 + col)*256 + ko);
            accA = MFMA16(a, bb, accA);
            if (w == 0){
                short8 b2 = ld8(RT + (64 + col)*256 + ko);
                accB = MFMA16(a, b2, accB);
            }
        }
        __syncthreads();                                // all sE reads done
        float* sH = (float*)sBuf;                       // [16][40] heads staging
        #pragma unroll
        for (int r = 0; r < 4; ++r){
            float v = accA[r];
            float o = __shfl_xor(v, 1, 64);
            if (!(col & 1)){
                const int f = w*8 + (col >> 1);
                float num = v, den = o, h;
                if (den != 0.0f) h = num/den;
                else {
                    float s = 0.f;
                    for (int k = 0; k < NTK; ++k) s += value[(b*NTK + k)*NF + f];
                    h = s * (1.0f/256.0f);
                }
                sH[(quad*4 + r)*40 + f] = h;
            }
        }
        if (w == 0){
            #pragma unroll
            for (int r = 0; r < 4; ++r){
                float v = accB[r];
                float o = __shfl_xor(v, 1, 64);
                if (!(col & 1)){
                    const int f = 32 + (col >> 1);
                    if (f < NF){
                        float num = v, den = o, h;
                        if (den != 0.0f) h = num/den;
                        else {
                            float s = 0.f;
                            for (int k = 0; k < NTK; ++k) s += value[(b*NTK + k)*NF + f];
                            h = s * (1.0f/256.0f);
                        }
                        sH[(quad*4 + r)*40 + f] = h;
                    }
                }
            }
        }
        __syncthreads();
        for (int idx = tid; idx < 16*NF; idx += 256){
            const int q = idx/NF, f = idx - q*NF;
            HD[(t0 + q)*NF + f] = sH[q*40 + f];
        }
    }
    gridbar(cnts + 2);

    // ---------------- phase D: fused head-mix MLP (8 units/block) ----------------
    {
        const float* hd = (const float*)(wsb + HD_OFF);
        const int d = tid;
        float* shf = (float*)sBuf;                      // [288]
        float* sW1 = shf + NF*NH;                       // [216]
        if (tid < NF*NSF) sW1[tid] = Wo1[tid];
        float wcr[8];
        #pragma unroll
        for (int h = 0; h < 8; ++h) wcr[h] = Wc[h*ND + d];
        const float bcd = bc[d];
        float bo1r[6], wo2r[6];
        #pragma unroll
        for (int s = 0; s < 6; ++s){ bo1r[s] = bo1[s]; wo2r[s] = Wo2[s]; }
        const float bo2d = bo2[d];

        for (int i = 0; i < 8; ++i){
            const int unit = bid*8 + i;                 // 4096 units
            const int b = unit >> 8, qq = unit & 255;
            __syncthreads();                            // prior unit's shf reads done
            for (int t = tid; t < NF*NH; t += 256){
                int jj = t/NF, f = t - jj*NF;
                shf[t] = hd[((b*NH + jj)*NTQ + qq)*NF + f];
            }
            __syncthreads();
            float a2[6];
            #pragma unroll
            for (int s = 0; s < 6; ++s) a2[s] = bo1r[s];
            #pragma unroll
            for (int f4 = 0; f4 < NF; f4 += 4){
                float4 sv[8];
                #pragma unroll
                for (int h = 0; h < 8; ++h) sv[h] = *(const float4*)&shf[h*NF + f4];
                #pragma unroll
                for (int fi = 0; fi < 4; ++fi){
                    float a = bcd;
                    #pragma unroll
                    for (int h = 0; h < 8; ++h)
                        a = fmaf(reinterpret_cast<const float*>(&sv[h])[fi], wcr[h], a);
                    float lf = fast_tanh(a);
                    const int f = f4 + fi;
                    #pragma unroll
                    for (int s = 0; s < 6; ++s)
                        a2[s] = fmaf(lf, sW1[f*NSF + s], a2[s]);
                }
            }
            float o = bo2d;
            #pragma unroll
            for (int s = 0; s < 6; ++s)
                o = fmaf(fast_tanh(a2[s]), wo2r[s], o);
            out[(b*NTQ + qq)*ND + d] = o;
        }
    }
}

extern "C" void kernel_launch(void* const* d_in, const int* in_sizes, int n_in,
                              void* d_out, int out_size, void* d_ws, size_t ws_size,
                              hipStream_t stream){
    const float* query  = (const float*)d_in[0];
    const float* key_ts = (const float*)d_in[1];
    const float* value  = (const float*)d_in[2];
    const float* mask   = (const float*)d_in[3];
    const float* Wq     = (const float*)d_in[4];
    const float* Wk     = (const float*)d_in[5];
    const float* Wc     = (const float*)d_in[6];
    const float* bc     = (const float*)d_in[7];
    const float* Wo1    = (const float*)d_in[8];
    const float* bo1    = (const float*)d_in[9];
    const float* Wo2    = (const float*)d_in[10];
    const float* bo2    = (const float*)d_in[11];
    char* wsb  = (char*)d_ws;
    float* out = (float*)d_out;
    (void)in_sizes; (void)n_in; (void)out_size; (void)ws_size;

    // zero the grid-barrier counters (workspace is poisoned before each replay)
    hipMemsetAsync(wsb + CNT_OFF, 0, 256, stream);
    imta_all<<<dim3(NBLK), dim3(256), 0, stream>>>(query, key_ts, value, mask,
                                                   Wq, Wk, Wc, bc, Wo1, bo1, Wo2, bo2,
                                                   wsb, out);
}

// Round 6
// 142.616 us; speedup vs baseline: 2.6228x; 2.6228x over previous
//
#include <hip/hip_runtime.h>

#define NB 16
#define NTQ 256
#define NTK 256
#define ND 256
#define NF 36
#define NH 8
#define NDK 32
#define NSF 6

typedef __attribute__((ext_vector_type(8))) short short8;
typedef __attribute__((ext_vector_type(4))) float f32x4;
#define MFMA16(a,b,c) __builtin_amdgcn_mfma_f32_16x16x32_bf16(a,b,c,0,0,0)

// ---- workspace byte offsets ----
// RT: [b][80][256] bf16 (f'=2f: m*v, f'=2f+1: m)
#define RT_OFF   524288u
// projected Q/K hi/lo: [b][j][t][dk] bf16, 4MB each
#define QPH_OFF  (2u*1024*1024)
#define QPL_OFF  (6u*1024*1024)
#define KPH_OFF  (10u*1024*1024)
#define KPL_OFF  (14u*1024*1024)
// HD: fp32 [b][j][t][f]
#define HD_OFF   (18u*1024*1024)

__device__ __forceinline__ short f2bf(float x){
    union { float f; unsigned u; } v; v.f = x;
    unsigned r = v.u + 0x7fffu + ((v.u >> 16) & 1u);
    return (short)(r >> 16);
}
__device__ __forceinline__ float bf2f(short s){
    union { float f; unsigned u; } v; v.u = ((unsigned)(unsigned short)s) << 16;
    return v.f;
}
__device__ __forceinline__ float fast_tanh(float x){
    float e = __expf(2.0f*x);
    return 1.0f - 2.0f/(e + 1.0f);
}
__device__ __forceinline__ short8 ld8(const short* p){ return *(const short8*)p; }

// hi/lo bf16 split of 8 consecutive floats (RNE hi, RNE residual lo)
__device__ __forceinline__ void cvt8(const float* __restrict__ p, short8& h8, short8& l8){
    f32x4 a = *(const f32x4*)p;
    f32x4 c = *(const f32x4*)(p + 4);
    #pragma unroll
    for (int i = 0; i < 4; ++i){
        short h0 = f2bf(a[i]); h8[i]   = h0; l8[i]   = f2bf(a[i] - bf2f(h0));
        short h1 = f2bf(c[i]); h8[4+i] = h1; l8[4+i] = f2bf(c[i] - bf2f(h1));
    }
}

// ---------------- kernel 1: projection GEMM (W staged in LDS) + RT pack ----------------
// bid < 1024: proj. b=bid>>6, side=(bid>>5)&1, j=(bid>>2)&7, t0=(bid&3)*64.
//   Stage W[j] (fp32, global) -> LDS hi/lo [dk][d] once (1 barrier), then wave w
//   computes rows [t0+16w, t0+16w+16) x 32 cols: per kb {cvt8(X) ; 2x ld8 LDS ; 6 MFMA}.
//   Same per-output MFMA accumulation order as verified rounds -> bit-identical.
// bid >= 1024: RT pack (verbatim).
__global__ __launch_bounds__(256, 4)
void imta_proj(const float* __restrict__ query, const float* __restrict__ key_ts,
               const float* __restrict__ Wq, const float* __restrict__ Wk,
               const float* __restrict__ mask, const float* __restrict__ value,
               char* __restrict__ wsb){
    const int bid = blockIdx.x, tid = threadIdx.x;
    if (bid >= 1024){
        const int rb = bid - 1024;
        const int x = rb & 15, b = rb >> 4;
        const int k = tid;
        short* rt = (short*)(wsb + RT_OFF) + b*80*256;
        #pragma unroll
        for (int r = 0; r < 5; ++r){
            const int fp = x*5 + r;
            const int f = fp >> 1;
            short o = 0;
            if (f < NF){
                float m = mask[(b*NTK + k)*NF + f];
                o = (fp & 1) ? f2bf(m) : f2bf(m * value[(b*NTK + k)*NF + f]);
            }
            rt[fp*256 + k] = o;
        }
        return;
    }
    const int b = bid >> 6, side = (bid >> 5) & 1, j = (bid >> 2) & 7;
    const int t0 = (bid & 3)*64;
    const int w = tid >> 6, lane = tid & 63;
    const int col = lane & 15, quad = lane >> 4;

    __shared__ __align__(16) short sW[2*32*264];     // hi | lo, [dk][264-padded d]
    short* const sWH = sW;
    short* const sWL = sW + 32*264;

    const float* __restrict__ X = side ? key_ts : query;
    const float* __restrict__ W = (side ? Wk : Wq) + (size_t)j*ND*NDK;
    short* OH = (short*)(wsb + (side ? KPH_OFF : QPH_OFF));
    short* OL = (short*)(wsb + (side ? KPL_OFF : QPL_OFF));

    // stage W[j]: thread covers dk0=(tid&7)*4, d=tid>>3 (+32 per iter), coalesced f32x4
    {
        const int dk0 = (tid & 7)*4, dbase = tid >> 3;
        #pragma unroll
        for (int it = 0; it < 8; ++it){
            const int d = dbase + it*32;
            f32x4 wv = *(const f32x4*)(W + (size_t)d*NDK + dk0);
            #pragma unroll
            for (int i = 0; i < 4; ++i){
                short h = f2bf(wv[i]);
                sWH[(dk0 + i)*264 + d] = h;
                sWL[(dk0 + i)*264 + d] = f2bf(wv[i] - bf2f(h));
            }
        }
    }
    __syncthreads();

    const int row = t0 + w*16 + col;
    const float* xrow = X + (size_t)(b*NTQ + row)*ND;
    f32x4 acc[2]; acc[0] = (f32x4)0.f; acc[1] = (f32x4)0.f;
    #pragma unroll
    for (int kb = 0; kb < 8; ++kb){
        const int dko = kb*32 + quad*8;
        short8 ah, al;
        cvt8(xrow + dko, ah, al);
        #pragma unroll
        for (int nt = 0; nt < 2; ++nt){
            short8 bh = *(const short8*)&sWH[(nt*16 + col)*264 + dko];
            short8 bl = *(const short8*)&sWL[(nt*16 + col)*264 + dko];
            acc[nt] = MFMA16(al, bh, acc[nt]);
            acc[nt] = MFMA16(ah, bl, acc[nt]);
            acc[nt] = MFMA16(ah, bh, acc[nt]);
        }
    }
    #pragma unroll
    for (int nt = 0; nt < 2; ++nt){
        const int dk = nt*16 + col;
        #pragma unroll
        for (int r = 0; r < 4; ++r){
            const int t = t0 + w*16 + quad*4 + r;
            float v = acc[nt][r];
            short h = f2bf(v);
            size_t o = (size_t)(((b*NH + j)*NTQ + t)*NDK + dk);
            OH[o] = h; OL[o] = f2bf(v - bf2f(h));
        }
    }
}

// ---------------- kernel 2: attention (R3-verified 16-q, 2048 blocks) ----------------
// grid (16, 8, 16): x = q-tile (16 rows), y = j, z = b. 256 thr = 4 waves.
// phase1: wave w -> keys [64w, 64w+64) (3-pass hi/lo scores) -> exp -> sE
// phase2: wave w -> f-tile nt=w (wave 0 also nt=4), full K; shfl div -> sH -> HD
__global__ __launch_bounds__(256, 8)
void imta_attn(char* __restrict__ wsb, const float* __restrict__ value){
    const int t0 = blockIdx.x*16;
    const int j = blockIdx.y, b = blockIdx.z;
    const int tid = threadIdx.x, w = tid >> 6, lane = tid & 63;
    const int col = lane & 15, quad = lane >> 4;
    __shared__ __align__(16) short sE[16*264];     // 8.25 KB; overlaid by sH
    const short* QH = (const short*)(wsb + QPH_OFF) + (b*NH + j)*NTQ*NDK;
    const short* QL = (const short*)(wsb + QPL_OFF) + (b*NH + j)*NTQ*NDK;
    const short* KH = (const short*)(wsb + KPH_OFF) + (b*NH + j)*NTK*NDK;
    const short* KL = (const short*)(wsb + KPL_OFF) + (b*NH + j)*NTK*NDK;
    const short* RT = (const short*)(wsb + RT_OFF) + b*80*256;
    float* HD = (float*)(wsb + HD_OFF) + (b*NH + j)*NTQ*NF;

    short8 ah = ld8(QH + (t0 + col)*NDK + quad*8);
    short8 al = ld8(QL + (t0 + col)*NDK + quad*8);
    #pragma unroll
    for (int nt = 0; nt < 4; ++nt){
        const int key0 = w*64 + nt*16;
        short8 bh = ld8(KH + (key0 + col)*NDK + quad*8);
        short8 bl = ld8(KL + (key0 + col)*NDK + quad*8);
        f32x4 c = (f32x4)0.f;
        c = MFMA16(al, bh, c);
        c = MFMA16(ah, bl, c);
        c = MFMA16(ah, bh, c);
        const int key = key0 + col;
        #pragma unroll
        for (int r = 0; r < 4; ++r)
            sE[(quad*4 + r)*264 + key] = f2bf(__expf(c[r]));
    }
    __syncthreads();

    f32x4 accA = (f32x4)0.f, accB = (f32x4)0.f;
    #pragma unroll 2
    for (int kb = 0; kb < 8; ++kb){
        const int ko = kb*32 + quad*8;
        short8 a = *(const short8*)&sE[col*264 + ko];
        short8 bb = ld8(RT + (w*16 + col)*256 + ko);
        accA = MFMA16(a, bb, accA);
        if (w == 0){
            short8 b2 = ld8(RT + (64 + col)*256 + ko);
            accB = MFMA16(a, b2, accB);
        }
    }
    __syncthreads();                           // all phase-2 sE reads done
    float* sH = (float*)sE;                    // [16][40] heads staging
    #pragma unroll
    for (int r = 0; r < 4; ++r){
        float v = accA[r];
        float o = __shfl_xor(v, 1, 64);
        if (!(col & 1)){
            const int f = w*8 + (col >> 1);
            float num = v, den = o, h;
            if (den != 0.0f) h = num/den;
            else {
                float s = 0.f;
                for (int k = 0; k < NTK; ++k) s += value[(b*NTK + k)*NF + f];
                h = s * (1.0f/256.0f);
            }
            sH[(quad*4 + r)*40 + f] = h;
        }
    }
    if (w == 0){
        #pragma unroll
        for (int r = 0; r < 4; ++r){
            float v = accB[r];
            float o = __shfl_xor(v, 1, 64);
            if (!(col & 1)){
                const int f = 32 + (col >> 1);
                if (f < NF){
                    float num = v, den = o, h;
                    if (den != 0.0f) h = num/den;
                    else {
                        float s = 0.f;
                        for (int k = 0; k < NTK; ++k) s += value[(b*NTK + k)*NF + f];
                        h = s * (1.0f/256.0f);
                    }
                    sH[(quad*4 + r)*40 + f] = h;
                }
            }
        }
    }
    __syncthreads();
    for (int idx = tid; idx < 16*NF; idx += 256){
        const int q = idx/NF, f = idx - q*NF;
        HD[(t0 + q)*NF + f] = sH[q*40 + f];
    }
}

// ---------------- kernel 3: fused head-mix MLP ----------------
__global__ void imta_final(const float* __restrict__ Wc, const float* __restrict__ bc,
                           const float* __restrict__ Wo1, const float* __restrict__ bo1,
                           const float* __restrict__ Wo2, const float* __restrict__ bo2,
                           const float* __restrict__ hd, float* __restrict__ out){
    const int bq = blockIdx.x;
    const int b = bq >> 8, qq = bq & 255;
    const int tid = threadIdx.x;
    __shared__ float sh[NF*NH];
    __shared__ float sW1[NF*NSF];
    for (int t = tid; t < NF*NH; t += 256){
        int jj = t/NF, f = t - jj*NF;
        sh[t] = hd[((b*NH + jj)*NTQ + qq)*NF + f];
    }
    if (tid < NF*NSF) sW1[tid] = Wo1[tid];
    __syncthreads();
    const int d = tid;
    float wcr[8];
    #pragma unroll
    for (int h = 0; h < 8; ++h) wcr[h] = Wc[h*ND + d];
    const float bcd = bc[d];
    float a2[6];
    #pragma unroll
    for (int s = 0; s < 6; ++s) a2[s] = bo1[s];
    #pragma unroll
    for (int f4 = 0; f4 < NF; f4 += 4){
        float4 sv[8];
        #pragma unroll
        for (int h = 0; h < 8; ++h) sv[h] = *(const float4*)&sh[h*NF + f4];
        #pragma unroll
        for (int fi = 0; fi < 4; ++fi){
            float a = bcd;
            #pragma unroll
            for (int h = 0; h < 8; ++h)
                a = fmaf(reinterpret_cast<const float*>(&sv[h])[fi], wcr[h], a);
            float lf = fast_tanh(a);
            const int f = f4 + fi;
            #pragma unroll
            for (int s = 0; s < 6; ++s)
                a2[s] = fmaf(lf, sW1[f*NSF + s], a2[s]);
        }
    }
    float o = bo2[d];
    #pragma unroll
    for (int s = 0; s < 6; ++s)
        o = fmaf(fast_tanh(a2[s]), Wo2[s], o);
    out[(b*NTQ + qq)*ND + d] = o;
}

extern "C" void kernel_launch(void* const* d_in, const int* in_sizes, int n_in,
                              void* d_out, int out_size, void* d_ws, size_t ws_size,
                              hipStream_t stream){
    const float* query  = (const float*)d_in[0];
    const float* key_ts = (const float*)d_in[1];
    const float* value  = (const float*)d_in[2];
    const float* mask   = (const float*)d_in[3];
    const float* Wq     = (const float*)d_in[4];
    const float* Wk     = (const float*)d_in[5];
    const float* Wc     = (const float*)d_in[6];
    const float* bc     = (const float*)d_in[7];
    const float* Wo1    = (const float*)d_in[8];
    const float* bo1    = (const float*)d_in[9];
    const float* Wo2    = (const float*)d_in[10];
    const float* bo2    = (const float*)d_in[11];
    char* wsb  = (char*)d_ws;
    float* out = (float*)d_out;
    (void)in_sizes; (void)n_in; (void)out_size; (void)ws_size;

    imta_proj <<<dim3(1280),     dim3(256), 0, stream>>>(query, key_ts, Wq, Wk, mask, value, wsb);
    imta_attn <<<dim3(16, 8, 16),dim3(256), 0, stream>>>(wsb, value);
    imta_final<<<dim3(4096),     dim3(256), 0, stream>>>(Wc, bc, Wo1, bo1, Wo2, bo2,
                                                         (const float*)(wsb + HD_OFF), out);
}